// Round 2
// baseline (2338.213 us; speedup 1.0000x reference)
//
#include <hip/hip_runtime.h>

#define NN 100000
#define EE 1600000

typedef unsigned short ushortT;
typedef unsigned int uintT;

__device__ inline float bf2f(ushortT b) {
    uintT u = ((uintT)b) << 16;
    return __uint_as_float(u);
}
__device__ inline ushortT f2bf(float f) {
    uintT u = __float_as_uint(f);
    u += 0x7FFFu + ((u >> 16) & 1u);  // round-to-nearest-even
    return (ushortT)(u >> 16);
}

__device__ inline float4 load4f(const float* p) { return *reinterpret_cast<const float4*>(p); }
__device__ inline float4 load4f(const ushortT* p) {
    ushort4 u = *reinterpret_cast<const ushort4*>(p);
    return make_float4(bf2f(u.x), bf2f(u.y), bf2f(u.z), bf2f(u.w));
}

// ---------------------------------------------------------------------------
// pack W[r][k][o] (+ root[k][o]) into B[k][m], m = r*128+o for r<3, 384+o root
// ---------------------------------------------------------------------------
__global__ void pack_w_kernel(const float* __restrict__ W, const float* __restrict__ root,
                              float* __restrict__ B, int K) {
    int idx = blockIdx.x * blockDim.x + threadIdx.x;
    if (idx >= K * 512) return;
    int k = idx >> 9;
    int m = idx & 511;
    float v;
    if (m < 384) {
        int r = m >> 7, o = m & 127;
        v = W[((size_t)r * K + k) * 128 + o];
    } else {
        v = root[(size_t)k * 128 + (m - 384)];
    }
    B[idx] = v;
}

// ---------------------------------------------------------------------------
// count incoming edges per (dst, rel)
// ---------------------------------------------------------------------------
__global__ __launch_bounds__(256) void count_kernel(const int* __restrict__ edst,
                                                    const int* __restrict__ etyp,
                                                    float* __restrict__ cnt) {
    int e = blockIdx.x * blockDim.x + threadIdx.x;
    if (e >= EE) return;
    int d = edst[e], r = etyp[e];
    if ((unsigned)d >= NN || (unsigned)r >= 3u) return;
    atomicAdd(&cnt[d * 3 + r], 1.0f);
}

// ---------------------------------------------------------------------------
// C[N,512](bf16) = A[N,K] @ B[K,512]  (f32 math, 64x64 tile, 4x4/thr, 256 thr)
// ---------------------------------------------------------------------------
template <int K, typename TA>
__global__ __launch_bounds__(256) void gemm_kernel(const TA* __restrict__ A,
                                                   const float* __restrict__ B,
                                                   ushortT* __restrict__ C, int N) {
    __shared__ float As[16][65];  // [k][m], +1 pad
    __shared__ float Bs[16][65];  // [k][n], +1 pad

    const int bm = blockIdx.x * 64;
    const int bn = blockIdx.y * 64;
    const int tid = threadIdx.x;
    const int tm = (tid >> 4) << 2;
    const int tn = (tid & 15) << 2;

    float acc[4][4] = {};

    const int ar = tid >> 2;         // 0..63 A row in tile
    const int ac = (tid & 3) << 2;   // 0,4,8,12 A col in k-tile
    const int br = tid >> 4;         // 0..15 B row in k-tile
    const int bc = (tid & 15) << 2;  // 0..60 B col in tile

    for (int k0 = 0; k0 < K; k0 += 16) {
        float4 av = make_float4(0.f, 0.f, 0.f, 0.f);
        int arow = bm + ar;
        if (arow < N) av = load4f(&A[(size_t)arow * K + k0 + ac]);
        As[ac + 0][ar] = av.x;
        As[ac + 1][ar] = av.y;
        As[ac + 2][ar] = av.z;
        As[ac + 3][ar] = av.w;

        float4 bv = load4f(&B[(size_t)(k0 + br) * 512 + bn + bc]);
        Bs[br][bc + 0] = bv.x;
        Bs[br][bc + 1] = bv.y;
        Bs[br][bc + 2] = bv.z;
        Bs[br][bc + 3] = bv.w;

        __syncthreads();

#pragma unroll
        for (int kk = 0; kk < 16; ++kk) {
            float a0 = As[kk][tm + 0], a1 = As[kk][tm + 1];
            float a2 = As[kk][tm + 2], a3 = As[kk][tm + 3];
            float b0 = Bs[kk][tn + 0], b1 = Bs[kk][tn + 1];
            float b2 = Bs[kk][tn + 2], b3 = Bs[kk][tn + 3];
            acc[0][0] += a0 * b0; acc[0][1] += a0 * b1; acc[0][2] += a0 * b2; acc[0][3] += a0 * b3;
            acc[1][0] += a1 * b0; acc[1][1] += a1 * b1; acc[1][2] += a1 * b2; acc[1][3] += a1 * b3;
            acc[2][0] += a2 * b0; acc[2][1] += a2 * b1; acc[2][2] += a2 * b2; acc[2][3] += a2 * b3;
            acc[3][0] += a3 * b0; acc[3][1] += a3 * b1; acc[3][2] += a3 * b2; acc[3][3] += a3 * b3;
        }
        __syncthreads();
    }

#pragma unroll
    for (int i = 0; i < 4; ++i) {
        int row = bm + tm + i;
        if (row < N) {
            ushort4 v;
            v.x = f2bf(acc[i][0]);
            v.y = f2bf(acc[i][1]);
            v.z = f2bf(acc[i][2]);
            v.w = f2bf(acc[i][3]);
            *reinterpret_cast<ushort4*>(&C[(size_t)row * 512 + bn + tn]) = v;
        }
    }
}

// ---------------------------------------------------------------------------
// per-edge gather (bf16) + mean-weighted atomic scatter into agg[dst*128 + j]
// ---------------------------------------------------------------------------
__global__ __launch_bounds__(256) void edge_kernel(const int* __restrict__ esrc,
                                                   const int* __restrict__ edst,
                                                   const int* __restrict__ etyp,
                                                   const ushortT* __restrict__ trans,
                                                   const float* __restrict__ cnt,
                                                   float* __restrict__ agg) {
    int e = blockIdx.x * 2 + (threadIdx.x >> 7);
    if (e >= EE) return;
    int lane = threadIdx.x & 127;
    int s = esrc[e], d = edst[e], r = etyp[e];
    if ((unsigned)s >= NN || (unsigned)d >= NN || (unsigned)r >= 3u) return;
    float inv = 1.0f / fmaxf(cnt[d * 3 + r], 1.0f);
    float v = bf2f(trans[(size_t)s * 512 + r * 128 + lane]);
    atomicAdd(&agg[(size_t)d * 128 + lane], v * inv);
}

// ---------------------------------------------------------------------------
// block-of-128 mean/var (two waves)
// ---------------------------------------------------------------------------
__device__ inline void block_stats_128(float v, float& mu, float& rstd, float* sbuf) {
    float s = v, s2 = v * v;
#pragma unroll
    for (int m = 32; m >= 1; m >>= 1) {
        s += __shfl_xor(s, m);
        s2 += __shfl_xor(s2, m);
    }
    int w = threadIdx.x >> 6;
    if ((threadIdx.x & 63) == 0) { sbuf[w] = s; sbuf[2 + w] = s2; }
    __syncthreads();
    float ts = sbuf[0] + sbuf[1];
    float ts2 = sbuf[2] + sbuf[3];
    __syncthreads();
    mu = ts * (1.0f / 128.0f);
    float var = ts2 * (1.0f / 128.0f) - mu * mu;
    rstd = rsqrtf(var + 1e-5f);
}

// ---------------------------------------------------------------------------
// finalize layer 0: agg + root + bias -> LN -> leaky relu -> h1 (bf16)
// ---------------------------------------------------------------------------
__global__ __launch_bounds__(128) void finalize0_kernel(const ushortT* __restrict__ trans,
                                                        const float* __restrict__ agg,
                                                        const float* __restrict__ b0,
                                                        const float* __restrict__ g0,
                                                        const float* __restrict__ be0,
                                                        ushortT* __restrict__ h1) {
    __shared__ float sbuf[4];
    int n = blockIdx.x;
    int j = threadIdx.x;
    float v = agg[(size_t)n * 128 + j] + bf2f(trans[(size_t)n * 512 + 384 + j]) + b0[j];
    float mu, rstd;
    block_stats_128(v, mu, rstd, sbuf);
    v = (v - mu) * rstd * g0[j] + be0[j];
    v = v > 0.f ? v : 0.2f * v;
    h1[(size_t)n * 128 + j] = f2bf(v);
}

// ---------------------------------------------------------------------------
// finalize layer 1: agg + root + bias -> LN(g1,be1) -> LN(gout,bout) -> out f32
// ---------------------------------------------------------------------------
__global__ __launch_bounds__(128) void finalize1_kernel(const ushortT* __restrict__ trans,
                                                        const float* __restrict__ agg,
                                                        const float* __restrict__ b1,
                                                        const float* __restrict__ g1,
                                                        const float* __restrict__ be1,
                                                        const float* __restrict__ gout,
                                                        const float* __restrict__ bout,
                                                        float* __restrict__ out) {
    __shared__ float sbuf[4];
    int n = blockIdx.x;
    int j = threadIdx.x;
    float v = agg[(size_t)n * 128 + j] + bf2f(trans[(size_t)n * 512 + 384 + j]) + b1[j];
    float mu, rstd;
    block_stats_128(v, mu, rstd, sbuf);
    float y = (v - mu) * rstd * g1[j] + be1[j];
    block_stats_128(y, mu, rstd, sbuf);
    out[(size_t)n * 128 + j] = (y - mu) * rstd * gout[j] + bout[j];
}

// ---------------------------------------------------------------------------
extern "C" void kernel_launch(void* const* d_in, const int* in_sizes, int n_in,
                              void* d_out, int out_size, void* d_ws, size_t ws_size,
                              hipStream_t stream) {
    const float* x     = (const float*)d_in[0];
    const int*   eidx  = (const int*)d_in[1];
    const int*   etyp  = (const int*)d_in[2];
    const float* W0    = (const float*)d_in[3];
    const float* root0 = (const float*)d_in[4];
    const float* b0    = (const float*)d_in[5];
    const float* g0    = (const float*)d_in[6];
    const float* be0   = (const float*)d_in[7];
    const float* W1    = (const float*)d_in[8];
    const float* root1 = (const float*)d_in[9];
    const float* b1    = (const float*)d_in[10];
    const float* g1    = (const float*)d_in[11];
    const float* be1   = (const float*)d_in[12];
    const float* gout  = (const float*)d_in[13];
    const float* bout  = (const float*)d_in[14];

    const int* esrc = eidx;        // edge_index[0]
    const int* edst = eidx + EE;   // edge_index[1]

    // workspace layout (~181 MB), guard against undersized d_ws
    const size_t sz_trans = (size_t)NN * 512 * 2;   // 102.4 MB bf16
    const size_t sz_agg   = (size_t)NN * 128 * 4;   //  51.2 MB f32
    const size_t sz_cnt   = (size_t)NN * 3 * 4;     //   1.2 MB f32
    const size_t sz_h1    = (size_t)NN * 128 * 2;   //  25.6 MB bf16
    const size_t sz_bcat  = (size_t)256 * 512 * 4;  //   0.5 MB f32
    if (ws_size < sz_trans + sz_agg + sz_cnt + sz_h1 + sz_bcat) return;  // diagnostic: absmax≈5.03

    char* ws = (char*)d_ws;
    ushortT* trans = (ushortT*)ws; ws += sz_trans;
    float*   agg   = (float*)ws;   ws += sz_agg;
    float*   cnt   = (float*)ws;   ws += sz_cnt;
    ushortT* h1    = (ushortT*)ws; ws += sz_h1;
    float*   Bcat  = (float*)ws;   ws += sz_bcat;

    hipMemsetAsync(cnt, 0, sz_cnt, stream);
    hipMemsetAsync(agg, 0, sz_agg, stream);
    count_kernel<<<(EE + 255) / 256, 256, 0, stream>>>(edst, etyp, cnt);

    dim3 gemm_grid((NN + 63) / 64, 8);

    // ---- layer 0 (in=256) ----
    pack_w_kernel<<<(256 * 512 + 255) / 256, 256, 0, stream>>>(W0, root0, Bcat, 256);
    gemm_kernel<256, float><<<gemm_grid, 256, 0, stream>>>(x, Bcat, trans, NN);
    edge_kernel<<<EE / 2, 256, 0, stream>>>(esrc, edst, etyp, trans, cnt, agg);
    finalize0_kernel<<<NN, 128, 0, stream>>>(trans, agg, b0, g0, be0, h1);

    // ---- layer 1 (in=128) ----
    hipMemsetAsync(agg, 0, sz_agg, stream);
    pack_w_kernel<<<(128 * 512 + 255) / 256, 256, 0, stream>>>(W1, root1, Bcat, 128);
    gemm_kernel<128, ushortT><<<gemm_grid, 256, 0, stream>>>(h1, Bcat, trans, NN);
    edge_kernel<<<EE / 2, 256, 0, stream>>>(esrc, edst, etyp, trans, cnt, agg);
    finalize1_kernel<<<NN, 128, 0, stream>>>(trans, agg, b1, g1, be1, gout, bout,
                                             (float*)d_out);
}

// Round 3
// 622.224 us; speedup vs baseline: 3.7578x; 3.7578x over previous
//
#include <hip/hip_runtime.h>

#define NN 100000
#define EE 1600000

typedef unsigned short ushortT;
typedef unsigned int uintT;
typedef __attribute__((ext_vector_type(4))) float f32x4;
typedef __attribute__((ext_vector_type(8))) short bf16x8;

__device__ inline float bf2f(ushortT b) {
    return __uint_as_float(((uintT)b) << 16);
}
__device__ inline ushortT f2bf(float f) {
    uintT u = __float_as_uint(f);
    u += 0x7FFFu + ((u >> 16) & 1u);  // RNE
    return (ushortT)(u >> 16);
}

// ---------------------------------------------------------------------------
// histogram of edges per (dst, rel)
// ---------------------------------------------------------------------------
__global__ __launch_bounds__(256) void count3_kernel(const int* __restrict__ edst,
                                                     const int* __restrict__ etyp,
                                                     int* __restrict__ cnt3) {
    int e = blockIdx.x * blockDim.x + threadIdx.x;
    if (e >= EE) return;
    int d = edst[e], r = etyp[e];
    if ((unsigned)d >= NN || (unsigned)r >= 3u) return;
    atomicAdd(&cnt3[d * 3 + r], 1);
}

// ---------------------------------------------------------------------------
// exclusive scan of node degrees (deg = sum of cnt3 triple): 1 block, 1024 thr
// ---------------------------------------------------------------------------
__global__ __launch_bounds__(1024) void scan_kernel(const int* __restrict__ cnt3,
                                                    int* __restrict__ row_ptr) {
    __shared__ int wpart[16];
    __shared__ int s_carry;
    const int tid = threadIdx.x;
    const int lane = tid & 63, wid = tid >> 6;
    if (tid == 0) s_carry = 0;
    __syncthreads();
    for (int base = 0; base < NN; base += 1024) {
        int n = base + tid;
        int d = 0;
        if (n < NN) d = cnt3[n * 3] + cnt3[n * 3 + 1] + cnt3[n * 3 + 2];
        int v = d;  // inclusive scan within wave
#pragma unroll
        for (int off = 1; off < 64; off <<= 1) {
            int t = __shfl_up(v, off);
            if (lane >= off) v += t;
        }
        if (lane == 63) wpart[wid] = v;
        __syncthreads();
        if (wid == 0) {
            int p = (lane < 16) ? wpart[lane] : 0;
#pragma unroll
            for (int off = 1; off < 16; off <<= 1) {
                int t = __shfl_up(p, off);
                if (lane >= off) p += t;
            }
            if (lane < 16) wpart[lane] = p;
        }
        __syncthreads();
        int total = wpart[15];
        int wexcl = (wid == 0) ? 0 : wpart[wid - 1];
        int excl = s_carry + wexcl + (v - d);
        if (n < NN) row_ptr[n] = excl;
        __syncthreads();
        if (tid == 0) s_carry += total;
        __syncthreads();
    }
    if (tid == 0) row_ptr[NN] = s_carry;
}

// ---------------------------------------------------------------------------
// fill CSR edge list: elist[row_ptr[d] + cursor[d]++] = (src<<2)|rel
// ---------------------------------------------------------------------------
__global__ __launch_bounds__(256) void fill_kernel(const int* __restrict__ esrc,
                                                   const int* __restrict__ edst,
                                                   const int* __restrict__ etyp,
                                                   const int* __restrict__ row_ptr,
                                                   int* __restrict__ cursor,
                                                   uintT* __restrict__ elist) {
    int e = blockIdx.x * blockDim.x + threadIdx.x;
    if (e >= EE) return;
    int s = esrc[e], d = edst[e], r = etyp[e];
    if ((unsigned)s >= NN || (unsigned)d >= NN || (unsigned)r >= 3u) return;
    int pos = row_ptr[d] + atomicAdd(&cursor[d], 1);
    elist[pos] = ((uintT)s << 2) | (uintT)r;
}

// ---------------------------------------------------------------------------
// pack [W|root] into MFMA-fragment-ready bf16 layout:
// Bpack[((nblk*KB + kblk)*64 + lane)*8 + j] = Bsrc[kblk*32+(lane>>4)*8+j][nblk*16+(lane&15)]
// ---------------------------------------------------------------------------
template <int K>
__global__ __launch_bounds__(256) void bpack_kernel(const float* __restrict__ W,
                                                    const float* __restrict__ root,
                                                    ushortT* __restrict__ Bpack) {
    constexpr int KB = K / 32;
    int idx = blockIdx.x * blockDim.x + threadIdx.x;
    if (idx >= 512 * K) return;
    int j = idx & 7;
    int l = (idx >> 3) & 63;
    int blk = idx >> 9;          // nblk*KB + kblk
    int kb = blk % KB, nblk = blk / KB;
    int k = kb * 32 + (l >> 4) * 8 + j;
    int m = nblk * 16 + (l & 15);
    float v;
    if (m < 384) {
        v = W[(((size_t)(m >> 7)) * K + k) * 128 + (m & 127)];
    } else {
        v = root[(size_t)k * 128 + (m - 384)];
    }
    Bpack[idx] = f2bf(v);
}

// ---------------------------------------------------------------------------
// bf16 MFMA GEMM: C[N,512](bf16) = A[N,K] @ B[K,512]
// 128x128 tile, 4 waves (2x2), BK=32, A in swizzled LDS, B fragment-packed global
// ---------------------------------------------------------------------------
__device__ inline int swz_off(int r, int g) {  // ushort offset of 16B unit
    return r * 32 + ((g ^ ((r >> 1) & 3)) << 3);
}

template <int K, bool AF32>
__global__ __launch_bounds__(256) void gemm_mfma_kernel(const void* __restrict__ Aptr,
                                                        const ushortT* __restrict__ Bpack,
                                                        ushortT* __restrict__ C, int N) {
    constexpr int KB = K / 32;
    __shared__ ushortT As[128 * 32];  // 8 KB

    const int tid = threadIdx.x;
    const int lane = tid & 63;
    const int wid = tid >> 6;
    const int wr = wid >> 1, wc = wid & 1;
    const int bm = blockIdx.x * 128;
    const int bnblk = blockIdx.y * 8;  // base 16-col block

    const int st_r = tid >> 1;          // staging row 0..127
    const int st_g0 = (tid & 1) * 2;    // staging unit group {0,2}

    f32x4 acc[4][4] = {};
    bf16x8 breg[4], bnext[4], stg[2];

    // ---- staging loader (global -> regs) ----
    auto stage_load = [&](int k0, bf16x8* out) {
#pragma unroll
        for (int u = 0; u < 2; ++u) {
            int g = st_g0 + u;
            int row = bm + st_r;
            bf16x8 val = {};
            if (row < N) {
                if (AF32) {
                    const float* A = (const float*)Aptr;
                    const float4 lo = *(const float4*)&A[(size_t)row * K + k0 + g * 8];
                    const float4 hi = *(const float4*)&A[(size_t)row * K + k0 + g * 8 + 4];
                    val[0] = (short)f2bf(lo.x); val[1] = (short)f2bf(lo.y);
                    val[2] = (short)f2bf(lo.z); val[3] = (short)f2bf(lo.w);
                    val[4] = (short)f2bf(hi.x); val[5] = (short)f2bf(hi.y);
                    val[6] = (short)f2bf(hi.z); val[7] = (short)f2bf(hi.w);
                } else {
                    const ushortT* A = (const ushortT*)Aptr;
                    val = *(const bf16x8*)&A[(size_t)row * K + k0 + g * 8];
                }
            }
            out[u] = val;
        }
    };
    auto stage_write = [&](const bf16x8* v) {
#pragma unroll
        for (int u = 0; u < 2; ++u)
            *(bf16x8*)&As[swz_off(st_r, st_g0 + u)] = v[u];
    };
    auto load_b = [&](int kblk, bf16x8* out) {
#pragma unroll
        for (int nb = 0; nb < 4; ++nb) {
            int nblk = bnblk + wc * 4 + nb;
            out[nb] = *(const bf16x8*)&Bpack[((size_t)(nblk * KB + kblk) * 64 + lane) * 8];
        }
    };

    // prologue
    stage_load(0, stg);
    stage_write(stg);
    load_b(0, breg);

    for (int kblk = 0; kblk < KB; ++kblk) {
        __syncthreads();  // As ready
        bf16x8 afrag[4];
#pragma unroll
        for (int mb = 0; mb < 4; ++mb) {
            int fr = wr * 64 + mb * 16 + (lane & 15);
            int fg = lane >> 4;
            afrag[mb] = *(const bf16x8*)&As[swz_off(fr, fg)];
        }
        if (kblk + 1 < KB) {
            stage_load((kblk + 1) * 32, stg);
            load_b(kblk + 1, bnext);
        }
#pragma unroll
        for (int mb = 0; mb < 4; ++mb)
#pragma unroll
            for (int nb = 0; nb < 4; ++nb)
                acc[mb][nb] = __builtin_amdgcn_mfma_f32_16x16x32_bf16(
                    afrag[mb], breg[nb], acc[mb][nb], 0, 0, 0);
        __syncthreads();  // done reading As
        if (kblk + 1 < KB) {
            stage_write(stg);
#pragma unroll
            for (int nb = 0; nb < 4; ++nb) breg[nb] = bnext[nb];
        }
    }

    // epilogue: C/D layout col=lane&15, row=(lane>>4)*4+q   [guide m89/m91]
#pragma unroll
    for (int mb = 0; mb < 4; ++mb) {
        int row0 = bm + wr * 64 + mb * 16 + ((lane >> 4) << 2);
#pragma unroll
        for (int nb = 0; nb < 4; ++nb) {
            int col = (bnblk + wc * 4 + nb) * 16 + (lane & 15);
#pragma unroll
            for (int q = 0; q < 4; ++q) {
                int row = row0 + q;
                if (row < N) C[(size_t)row * 512 + col] = f2bf(acc[mb][nb][q]);
            }
        }
    }
}

// ---------------------------------------------------------------------------
// fused CSR aggregation + root + bias + LN (+leaky / +LN2): one wave per node
// LAYER 0: -> h1 bf16 (leaky relu).  LAYER 1: -> out f32 (double LN).
// ---------------------------------------------------------------------------
template <int LAYER>
__global__ __launch_bounds__(256) void agg_finalize_kernel(
    const ushortT* __restrict__ trans, const uintT* __restrict__ elist,
    const int* __restrict__ row_ptr, const int* __restrict__ cnt3,
    const float* __restrict__ bias, const float* __restrict__ gamma,
    const float* __restrict__ beta, const float* __restrict__ gout,
    const float* __restrict__ bout, void* __restrict__ outp) {
    const int wid = threadIdx.x >> 6;
    const int lane = threadIdx.x & 63;
    const int n = blockIdx.x * 4 + wid;  // grid sized exactly: 25000*4 = NN

    const int start = row_ptr[n];
    const int end = row_ptr[n + 1];
    const float i0 = 1.0f / fmaxf((float)cnt3[n * 3 + 0], 1.0f);
    const float i1 = 1.0f / fmaxf((float)cnt3[n * 3 + 1], 1.0f);
    const float i2 = 1.0f / fmaxf((float)cnt3[n * 3 + 2], 1.0f);

    float a0 = 0.f, a1 = 0.f;
    int i = start;
    for (; i + 1 < end; i += 2) {
        uintT v0 = elist[i], v1 = elist[i + 1];
        int s0 = v0 >> 2, r0 = v0 & 3;
        int s1 = v1 >> 2, r1 = v1 & 3;
        ushort2 u0 = *(const ushort2*)&trans[(size_t)s0 * 512 + r0 * 128 + lane * 2];
        ushort2 u1 = *(const ushort2*)&trans[(size_t)s1 * 512 + r1 * 128 + lane * 2];
        float w0 = r0 == 0 ? i0 : (r0 == 1 ? i1 : i2);
        float w1 = r1 == 0 ? i0 : (r1 == 1 ? i1 : i2);
        a0 += bf2f(u0.x) * w0 + bf2f(u1.x) * w1;
        a1 += bf2f(u0.y) * w0 + bf2f(u1.y) * w1;
    }
    if (i < end) {
        uintT v = elist[i];
        int s = v >> 2, r = v & 3;
        ushort2 u = *(const ushort2*)&trans[(size_t)s * 512 + r * 128 + lane * 2];
        float w = r == 0 ? i0 : (r == 1 ? i1 : i2);
        a0 += bf2f(u.x) * w;
        a1 += bf2f(u.y) * w;
    }

    // + root + bias
    ushort2 rt = *(const ushort2*)&trans[(size_t)n * 512 + 384 + lane * 2];
    float v0 = a0 + bf2f(rt.x) + bias[lane * 2 + 0];
    float v1 = a1 + bf2f(rt.y) + bias[lane * 2 + 1];

    // LN over 128 (each lane holds 2)
    float s = v0 + v1, s2 = v0 * v0 + v1 * v1;
#pragma unroll
    for (int m = 32; m >= 1; m >>= 1) {
        s += __shfl_xor(s, m);
        s2 += __shfl_xor(s2, m);
    }
    float mu = s * (1.0f / 128.0f);
    float rstd = rsqrtf(s2 * (1.0f / 128.0f) - mu * mu + 1e-5f);
    float y0 = (v0 - mu) * rstd * gamma[lane * 2 + 0] + beta[lane * 2 + 0];
    float y1 = (v1 - mu) * rstd * gamma[lane * 2 + 1] + beta[lane * 2 + 1];

    if (LAYER == 0) {
        y0 = y0 > 0.f ? y0 : 0.2f * y0;
        y1 = y1 > 0.f ? y1 : 0.2f * y1;
        ushort2 o;
        o.x = f2bf(y0);
        o.y = f2bf(y1);
        *(ushort2*)&((ushortT*)outp)[(size_t)n * 128 + lane * 2] = o;
    } else {
        float t = y0 + y1, t2 = y0 * y0 + y1 * y1;
#pragma unroll
        for (int m = 32; m >= 1; m >>= 1) {
            t += __shfl_xor(t, m);
            t2 += __shfl_xor(t2, m);
        }
        float mu2 = t * (1.0f / 128.0f);
        float rstd2 = rsqrtf(t2 * (1.0f / 128.0f) - mu2 * mu2 + 1e-5f);
        float2 o;
        o.x = (y0 - mu2) * rstd2 * gout[lane * 2 + 0] + bout[lane * 2 + 0];
        o.y = (y1 - mu2) * rstd2 * gout[lane * 2 + 1] + bout[lane * 2 + 1];
        *(float2*)&((float*)outp)[(size_t)n * 128 + lane * 2] = o;
    }
}

// ---------------------------------------------------------------------------
extern "C" void kernel_launch(void* const* d_in, const int* in_sizes, int n_in,
                              void* d_out, int out_size, void* d_ws, size_t ws_size,
                              hipStream_t stream) {
    const float* x     = (const float*)d_in[0];
    const int*   eidx  = (const int*)d_in[1];
    const int*   etyp  = (const int*)d_in[2];
    const float* W0    = (const float*)d_in[3];
    const float* root0 = (const float*)d_in[4];
    const float* b0    = (const float*)d_in[5];
    const float* g0    = (const float*)d_in[6];
    const float* be0   = (const float*)d_in[7];
    const float* W1    = (const float*)d_in[8];
    const float* root1 = (const float*)d_in[9];
    const float* b1    = (const float*)d_in[10];
    const float* g1    = (const float*)d_in[11];
    const float* be1   = (const float*)d_in[12];
    const float* gout  = (const float*)d_in[13];
    const float* bout  = (const float*)d_in[14];

    const int* esrc = eidx;
    const int* edst = eidx + EE;

    // workspace (~137 MB)
    const size_t sz_trans = (size_t)NN * 512 * 2;     // 102.4 MB
    const size_t sz_h1    = (size_t)NN * 128 * 2;     //  25.6 MB
    const size_t sz_bpack = (size_t)512 * 256 * 2;    //   0.25 MB
    const size_t sz_cnt3  = (size_t)NN * 3 * 4;       //   1.2 MB
    const size_t sz_rp    = (size_t)(NN + 1) * 4;     //   0.4 MB
    const size_t sz_cur   = (size_t)NN * 4;           //   0.4 MB
    const size_t sz_elist = (size_t)EE * 4;           //   6.4 MB
    if (ws_size < sz_trans + sz_h1 + sz_bpack + sz_cnt3 + sz_rp + sz_cur + sz_elist) return;

    char* ws = (char*)d_ws;
    ushortT* trans  = (ushortT*)ws; ws += sz_trans;
    ushortT* h1     = (ushortT*)ws; ws += sz_h1;
    ushortT* Bpack  = (ushortT*)ws; ws += sz_bpack;
    int*     cnt3   = (int*)ws;     ws += sz_cnt3;
    int*     rowp   = (int*)ws;     ws += sz_rp;
    int*     cursor = (int*)ws;     ws += sz_cur;
    uintT*   elist  = (uintT*)ws;   ws += sz_elist;

    hipMemsetAsync(cnt3, 0, sz_cnt3, stream);
    hipMemsetAsync(cursor, 0, sz_cur, stream);

    // ---- CSR build (shared by both layers) ----
    count3_kernel<<<(EE + 255) / 256, 256, 0, stream>>>(edst, etyp, cnt3);
    scan_kernel<<<1, 1024, 0, stream>>>(cnt3, rowp);
    fill_kernel<<<(EE + 255) / 256, 256, 0, stream>>>(esrc, edst, etyp, rowp, cursor, elist);

    dim3 ggrid((NN + 127) / 128, 4);

    // ---- layer 0 (K=256, A=f32 x) ----
    bpack_kernel<256><<<(512 * 256 + 255) / 256, 256, 0, stream>>>(W0, root0, Bpack);
    gemm_mfma_kernel<256, true><<<ggrid, 256, 0, stream>>>(x, Bpack, trans, NN);
    agg_finalize_kernel<0><<<NN / 4, 256, 0, stream>>>(trans, elist, rowp, cnt3, b0, g0, be0,
                                                       nullptr, nullptr, h1);

    // ---- layer 1 (K=128, A=bf16 h1) ----
    bpack_kernel<128><<<(512 * 128 + 255) / 256, 256, 0, stream>>>(W1, root1, Bpack);
    gemm_mfma_kernel<128, false><<<ggrid, 256, 0, stream>>>(h1, Bpack, trans, NN);
    agg_finalize_kernel<1><<<NN / 4, 256, 0, stream>>>(trans, elist, rowp, cnt3, b1, g1, be1,
                                                       gout, bout, d_out);
}